// Round 12
// baseline (204.545 us; speedup 1.0000x reference)
//
#include <hip/hip_runtime.h>

#define S_LEN 16
#define NMODEL 4096
#define DHEAD 128
#define HHEADS 32
#define MCACHE 8192
#define SPLITK 32
#define KSLICE (NMODEL / SPLITK)   // 128
#define CHUNK_W 32                 // rows per block (both waves share the chunk)
#define NCHT (MCACHE / CHUNK_W)    // 256 chunks per head

#define PART_ELEMS   ((size_t)3 * SPLITK * S_LEN * NMODEL)        // 6.29M floats
#define OPART_USH    ((size_t)HHEADS * NCHT * S_LEN * DHEAD)      // 16.78M ushorts
#define OPART_FLOATS (OPART_USH / 2)                              // 8.39M floats
#define REGION_ELEMS (PART_ELEMS > OPART_FLOATS ? PART_ELEMS : OPART_FLOATS)
#define STAT_ELEMS   ((size_t)HHEADS * NCHT * S_LEN)              // 131072

__device__ __forceinline__ unsigned short f2bf(float f) {
    unsigned int b = __float_as_uint(f);
    return (unsigned short)((b + 0x7FFFu + ((b >> 16) & 1u)) >> 16);   // RNE
}
__device__ __forceinline__ float bf2f(unsigned short u) {
    return __uint_as_float(((unsigned int)u) << 16);
}
__device__ __forceinline__ float dot8(const float4& a, const float4& b,
                                      const float4& x, const float4& y) {
    return a.x * x.x + a.y * x.y + a.z * x.z + a.w * x.w
         + b.x * y.x + b.y * y.y + b.z * y.z + b.w * y.w;
}

// ---------------- Kernel 1: split-K partial QKV projection ----------------
__global__ __launch_bounds__(256) void qkv_gemm(const float* __restrict__ X,
                                                const float* __restrict__ Wq,
                                                const float* __restrict__ Wk,
                                                const float* __restrict__ Wv,
                                                float* __restrict__ part) {
    const int tid   = threadIdx.x;
    const int col2  = blockIdx.x * 256 + tid;
    const int split = blockIdx.y;
    const int mat   = blockIdx.z;
    const float* __restrict__ W = (mat == 0) ? Wq : (mat == 1) ? Wk : Wv;
    const int k0 = split * KSLICE;

    __shared__ float Xs[KSLICE][S_LEN];     // 8 KB
    for (int i = tid; i < KSLICE * S_LEN; i += 256) {
        const int s = i & 15, k = i >> 4;
        Xs[k][s] = X[s * NMODEL + k0 + k];
    }
    __syncthreads();

    float2 acc[S_LEN];
#pragma unroll
    for (int s = 0; s < S_LEN; ++s) { acc[s].x = 0.f; acc[s].y = 0.f; }

    const float2* __restrict__ Wp = (const float2*)(W + (size_t)k0 * NMODEL) + col2;

#pragma unroll 8
    for (int k = 0; k < KSLICE; ++k) {
        const float2 w = Wp[(size_t)k * (NMODEL / 2)];
        const float4* __restrict__ xr = (const float4*)&Xs[k][0];
#pragma unroll
        for (int s4 = 0; s4 < 4; ++s4) {
            const float4 xv = xr[s4];
            acc[s4 * 4 + 0].x += xv.x * w.x;  acc[s4 * 4 + 0].y += xv.x * w.y;
            acc[s4 * 4 + 1].x += xv.y * w.x;  acc[s4 * 4 + 1].y += xv.y * w.y;
            acc[s4 * 4 + 2].x += xv.z * w.x;  acc[s4 * 4 + 2].y += xv.z * w.y;
            acc[s4 * 4 + 3].x += xv.w * w.x;  acc[s4 * 4 + 3].y += xv.w * w.y;
        }
    }

    float2* __restrict__ pp =
        (float2*)(part + (size_t)(mat * SPLITK + split) * S_LEN * NMODEL) + col2;
#pragma unroll
    for (int s = 0; s < S_LEN; ++s) pp[(size_t)s * (NMODEL / 2)] = acc[s];
}

// ---------------- Kernel 2: reduce split-K partials ----------------
__global__ __launch_bounds__(256) void qkv_reduce(const float* __restrict__ part,
                                                  float* __restrict__ qkv) {
    const int i4   = blockIdx.x * 256 + threadIdx.x;
    const int flat = i4 * 4;
    const int mat  = flat / (S_LEN * NMODEL);
    const int rem  = flat % (S_LEN * NMODEL);
    float4 sum = {0.f, 0.f, 0.f, 0.f};
#pragma unroll 8
    for (int sp = 0; sp < SPLITK; ++sp) {
        const float4 v = *(const float4*)(part +
            (size_t)(mat * SPLITK + sp) * (S_LEN * NMODEL) + rem);
        sum.x += v.x; sum.y += v.y; sum.z += v.z; sum.w += v.w;
    }
    *(float4*)(qkv + flat) = sum;
}

// ---------------- Kernel 3: fused single-pass flash attention ----------------
// grid = (NCHT=256, HHEADS=32) = 8192 blocks, block 128 = 2 INDEPENDENT waves.
// Wave wv handles s in [wv*8, wv*8+8). Lane = (sg=lane>>4 -> s pair
// {wv*8+sg*2, +1}, dsl=lane&15 -> dims dsl*8..+7). q,o,m,l all in registers;
// online softmax; zero LDS, zero barriers. K and V streams interleaved.
__global__ __launch_bounds__(128) void attn_partial(const float* __restrict__ qkv,
                                                    const float* __restrict__ cacheK,
                                                    const float* __restrict__ cacheV,
                                                    const int* __restrict__ Pp,
                                                    unsigned short* __restrict__ opart,
                                                    float* __restrict__ mstat,
                                                    float* __restrict__ lstat) {
    const int c    = blockIdx.x;
    const int h    = blockIdx.y;
    const int tid  = threadIdx.x;
    const int wv   = tid >> 6;
    const int lane = tid & 63;
    const int sg   = lane >> 4;
    const int dsl  = lane & 15;
    const int doff = dsl * 8;
    const int c0   = c * CHUNK_W;
    const int P    = *Pp;
    const int lo   = (P > c0) ? P : c0;
    const int hi_  = (P + S_LEN < c0 + CHUNK_W) ? (P + S_LEN) : (c0 + CHUNK_W);
    const bool overlap = (lo < hi_);
    const int s0   = wv * 8 + sg * 2;
    const int s1   = s0 + 1;

    const float* qb = qkv;
    const float* kb = qkv + S_LEN * NMODEL;
    const float* vb = qkv + 2 * S_LEN * NMODEL;

    const float4 q0a = *(const float4*)(qb + s0 * NMODEL + h * DHEAD + doff);
    const float4 q0b = *(const float4*)(qb + s0 * NMODEL + h * DHEAD + doff + 4);
    const float4 q1a = *(const float4*)(qb + s1 * NMODEL + h * DHEAD + doff);
    const float4 q1b = *(const float4*)(qb + s1 * NMODEL + h * DHEAD + doff + 4);

    const float* kbase = cacheK + ((size_t)h * MCACHE + c0) * DHEAD + doff;
    const float* vbase = cacheV + ((size_t)h * MCACHE + c0) * DHEAD + doff;

    float o0[8], o1[8];
#pragma unroll
    for (int k = 0; k < 8; ++k) { o0[k] = 0.f; o1[k] = 0.f; }
    float m0 = -1e30f, m1 = -1e30f, l0 = 0.f, l1 = 0.f;

#pragma unroll 4
    for (int m = 0; m < CHUNK_W; ++m) {
        const float4 ka = *(const float4*)(kbase + (size_t)m * DHEAD);
        const float4 kc = *(const float4*)(kbase + (size_t)m * DHEAD + 4);
        const float4 va = *(const float4*)(vbase + (size_t)m * DHEAD);
        const float4 vc = *(const float4*)(vbase + (size_t)m * DHEAD + 4);

        float d0 = dot8(ka, kc, q0a, q0b);
        float d1 = dot8(ka, kc, q1a, q1b);
#pragma unroll
        for (int off = 1; off <= 8; off <<= 1) {
            d0 += __shfl_xor(d0, off, 64);
            d1 += __shfl_xor(d1, off, 64);
        }

        if (d0 > m0) {                           // rare (≈4/32 rows), exec-masked
            const float sc = __expf(m0 - d0);
            m0 = d0; l0 *= sc;
#pragma unroll
            for (int k = 0; k < 8; ++k) o0[k] *= sc;
        }
        const float p0 = __expf(d0 - m0);
        l0 += p0;
        o0[0] += p0 * va.x; o0[1] += p0 * va.y; o0[2] += p0 * va.z; o0[3] += p0 * va.w;
        o0[4] += p0 * vc.x; o0[5] += p0 * vc.y; o0[6] += p0 * vc.z; o0[7] += p0 * vc.w;

        if (d1 > m1) {
            const float sc = __expf(m1 - d1);
            m1 = d1; l1 *= sc;
#pragma unroll
            for (int k = 0; k < 8; ++k) o1[k] *= sc;
        }
        const float p1 = __expf(d1 - m1);
        l1 += p1;
        o1[0] += p1 * va.x; o1[1] += p1 * va.y; o1[2] += p1 * va.z; o1[3] += p1 * va.w;
        o1[4] += p1 * vc.x; o1[5] += p1 * vc.y; o1[6] += p1 * vc.z; o1[7] += p1 * vc.w;
    }

    // ---- fixup for the chunk overlapping [P, P+S): replace stale K/V rows ----
    if (overlap) {
        for (int gm = lo; gm < hi_; ++gm) {
            const int i = gm - c0;
            const float* kfr = kb + (size_t)(gm - P) * NMODEL + h * DHEAD + doff;
            const float4 ksa = *(const float4*)(kbase + (size_t)i * DHEAD);
            const float4 ksc = *(const float4*)(kbase + (size_t)i * DHEAD + 4);
            const float4 kfa = *(const float4*)(kfr);
            const float4 kfc = *(const float4*)(kfr + 4);

            float ds0 = dot8(ksa, ksc, q0a, q0b);
            float ds1 = dot8(ksa, ksc, q1a, q1b);
            float dn0 = dot8(kfa, kfc, q0a, q0b);
            float dn1 = dot8(kfa, kfc, q1a, q1b);
#pragma unroll
            for (int off = 1; off <= 8; off <<= 1) {
                ds0 += __shfl_xor(ds0, off, 64);
                ds1 += __shfl_xor(ds1, off, 64);
                dn0 += __shfl_xor(dn0, off, 64);
                dn1 += __shfl_xor(dn1, off, 64);
            }
            if (dn0 > m0) {
                const float sc = __expf(m0 - dn0);
                m0 = dn0; l0 *= sc;
#pragma unroll
                for (int k = 0; k < 8; ++k) o0[k] *= sc;
            }
            if (dn1 > m1) {
                const float sc = __expf(m1 - dn1);
                m1 = dn1; l1 *= sc;
#pragma unroll
                for (int k = 0; k < 8; ++k) o1[k] *= sc;
            }
            const float pn0 = __expf(dn0 - m0), po0 = __expf(ds0 - m0);
            const float pn1 = __expf(dn1 - m1), po1 = __expf(ds1 - m1);
            l0 += pn0 - po0;
            l1 += pn1 - po1;

            const float* vfr = vb + (size_t)(gm - P) * NMODEL + h * DHEAD + doff;
            const float4 vsa = *(const float4*)(vbase + (size_t)i * DHEAD);
            const float4 vsc = *(const float4*)(vbase + (size_t)i * DHEAD + 4);
            const float4 vfa = *(const float4*)(vfr);
            const float4 vfc = *(const float4*)(vfr + 4);
            o0[0] += pn0 * vfa.x - po0 * vsa.x; o0[1] += pn0 * vfa.y - po0 * vsa.y;
            o0[2] += pn0 * vfa.z - po0 * vsa.z; o0[3] += pn0 * vfa.w - po0 * vsa.w;
            o0[4] += pn0 * vfc.x - po0 * vsc.x; o0[5] += pn0 * vfc.y - po0 * vsc.y;
            o0[6] += pn0 * vfc.z - po0 * vsc.z; o0[7] += pn0 * vfc.w - po0 * vsc.w;
            o1[0] += pn1 * vfa.x - po1 * vsa.x; o1[1] += pn1 * vfa.y - po1 * vsa.y;
            o1[2] += pn1 * vfa.z - po1 * vsa.z; o1[3] += pn1 * vfa.w - po1 * vsa.w;
            o1[4] += pn1 * vfc.x - po1 * vsc.x; o1[5] += pn1 * vfc.y - po1 * vsc.y;
            o1[6] += pn1 * vfc.z - po1 * vsc.z; o1[7] += pn1 * vfc.w - po1 * vsc.w;
        }
    }

    // ---- writes: opart bf16, stats from dsl==0 lanes ----
    const size_t ob = ((size_t)h * NCHT + c) * S_LEN * DHEAD;
    {
        uint4 pk;
        unsigned short* us = (unsigned short*)&pk;
#pragma unroll
        for (int k = 0; k < 8; ++k) us[k] = f2bf(o0[k]);
        *(uint4*)&opart[ob + (size_t)s0 * DHEAD + doff] = pk;
#pragma unroll
        for (int k = 0; k < 8; ++k) us[k] = f2bf(o1[k]);
        *(uint4*)&opart[ob + (size_t)s1 * DHEAD + doff] = pk;
    }
    if (dsl == 0) {
        mstat[((size_t)h * S_LEN + s0) * NCHT + c] = m0;
        lstat[((size_t)h * S_LEN + s0) * NCHT + c] = l0;
        mstat[((size_t)h * S_LEN + s1) * NCHT + c] = m1;
        lstat[((size_t)h * S_LEN + s1) * NCHT + c] = l1;
    }
}

// ---------------- Kernel 4: combine chunk partials ----------------
__global__ __launch_bounds__(512) void attn_combine(const unsigned short* __restrict__ opart,
                                                    const float* __restrict__ mstat,
                                                    const float* __restrict__ lstat,
                                                    float* __restrict__ out) {
    const int tid = threadIdx.x;
    const int cg  = tid >> 7;
    const int d   = tid & 127;
    const int s   = blockIdx.x;
    const int h   = blockIdx.y;

    __shared__ float mlds[NCHT], llds[NCHT], wlds[NCHT];
    __shared__ float olds[4][DHEAD];
    __shared__ float Llds[4];

    const size_t sb = ((size_t)h * S_LEN + s) * NCHT;
    if (tid < NCHT) { mlds[tid] = mstat[sb + tid]; llds[tid] = lstat[sb + tid]; }
    __syncthreads();

    float gmax = fmaxf(fmaxf(mlds[tid & 63], mlds[(tid & 63) + 64]),
                       fmaxf(mlds[(tid & 63) + 128], mlds[(tid & 63) + 192]));
    for (int off = 32; off > 0; off >>= 1) gmax = fmaxf(gmax, __shfl_xor(gmax, off, 64));

    if (tid < NCHT) wlds[tid] = __expf(mlds[tid] - gmax);
    __syncthreads();

    float o = 0.f, L = 0.f;
    for (int c = cg; c < NCHT; c += 4) {
        const float w = wlds[c];
        o += w * bf2f(opart[(((size_t)h * NCHT + c) * S_LEN + s) * DHEAD + d]);
        L += w * llds[c];
    }
    olds[cg][d] = o;
    if (d == 0) Llds[cg] = L;
    __syncthreads();

    if (tid < DHEAD) {
        const float ot = olds[0][tid] + olds[1][tid] + olds[2][tid] + olds[3][tid];
        const float Lt = Llds[0] + Llds[1] + Llds[2] + Llds[3];
        out[((size_t)h * S_LEN + s) * DHEAD + tid] = ot / Lt;
    }
}

extern "C" void kernel_launch(void* const* d_in, const int* in_sizes, int n_in,
                              void* d_out, int out_size, void* d_ws, size_t ws_size,
                              hipStream_t stream) {
    const float* X      = (const float*)d_in[0];
    const float* Wq     = (const float*)d_in[1];
    const float* Wk     = (const float*)d_in[2];
    const float* Wv     = (const float*)d_in[3];
    const float* cacheK = (const float*)d_in[4];
    const float* cacheV = (const float*)d_in[5];
    const int*   P      = (const int*)d_in[6];
    float* out = (float*)d_out;
    float* ws  = (float*)d_ws;

    float*          qkv   = ws;                                  // 196608 floats
    float*          part  = qkv + 3 * S_LEN * NMODEL;
    unsigned short* opart = (unsigned short*)part;               // aliases part
    float*          mstat = part + REGION_ELEMS;
    float*          lstat = mstat + STAT_ELEMS;

    qkv_gemm<<<dim3(8, SPLITK, 3), 256, 0, stream>>>(X, Wq, Wk, Wv, part);
    qkv_reduce<<<(3 * S_LEN * NMODEL / 4) / 256, 256, 0, stream>>>(part, qkv);
    attn_partial<<<dim3(NCHT, HHEADS), 128, 0, stream>>>(qkv, cacheK, cacheV, P,
                                                         opart, mstat, lstat);
    attn_combine<<<dim3(S_LEN, HHEADS), 512, 0, stream>>>(opart, mstat, lstat, out);
}

// Round 13
// 150.842 us; speedup vs baseline: 1.3560x; 1.3560x over previous
//
#include <hip/hip_runtime.h>

#define S_LEN 16
#define NMODEL 4096
#define DHEAD 128
#define HHEADS 32
#define MCACHE 8192
#define SPLITK 32
#define KSLICE (NMODEL / SPLITK)   // 128
#define CHUNK_W 64                 // rows per WAVE (4 MFMA row-tiles)
#define NCHT (MCACHE / CHUNK_W)    // 128 chunks per head
#define SPAD 20                    // sct row stride (mult of 4 for b128; 2-way banks)

#define PART_ELEMS   ((size_t)3 * SPLITK * S_LEN * NMODEL)        // 6.29M floats
#define OPART_USH    ((size_t)HHEADS * NCHT * S_LEN * DHEAD)      // 8.39M ushorts
#define OPART_FLOATS (OPART_USH / 2)                              // 4.19M floats
#define REGION_ELEMS (PART_ELEMS > OPART_FLOATS ? PART_ELEMS : OPART_FLOATS)
#define STAT_ELEMS   ((size_t)HHEADS * NCHT * S_LEN)              // 65536

typedef _Float16 half8 __attribute__((ext_vector_type(8)));
typedef float    f32x4 __attribute__((ext_vector_type(4)));

__device__ __forceinline__ half8 cvt8(float4 a, float4 b) {
    half8 h;
    h[0] = (_Float16)a.x; h[1] = (_Float16)a.y; h[2] = (_Float16)a.z; h[3] = (_Float16)a.w;
    h[4] = (_Float16)b.x; h[5] = (_Float16)b.y; h[6] = (_Float16)b.z; h[7] = (_Float16)b.w;
    return h;
}
__device__ __forceinline__ unsigned short f2h(float f) {
    _Float16 h = (_Float16)f; unsigned short u; __builtin_memcpy(&u, &h, 2); return u;
}
__device__ __forceinline__ float h2f(unsigned short u) {
    _Float16 h; __builtin_memcpy(&h, &u, 2); return (float)h;
}

// ---------------- Kernel 1: split-K partial QKV projection ----------------
__global__ __launch_bounds__(256) void qkv_gemm(const float* __restrict__ X,
                                                const float* __restrict__ Wq,
                                                const float* __restrict__ Wk,
                                                const float* __restrict__ Wv,
                                                float* __restrict__ part) {
    const int tid   = threadIdx.x;
    const int col2  = blockIdx.x * 256 + tid;
    const int split = blockIdx.y;
    const int mat   = blockIdx.z;
    const float* __restrict__ W = (mat == 0) ? Wq : (mat == 1) ? Wk : Wv;
    const int k0 = split * KSLICE;

    __shared__ float Xs[KSLICE][S_LEN];     // 8 KB
    for (int i = tid; i < KSLICE * S_LEN; i += 256) {
        const int s = i & 15, k = i >> 4;
        Xs[k][s] = X[s * NMODEL + k0 + k];
    }
    __syncthreads();

    float2 acc[S_LEN];
#pragma unroll
    for (int s = 0; s < S_LEN; ++s) { acc[s].x = 0.f; acc[s].y = 0.f; }

    const float2* __restrict__ Wp = (const float2*)(W + (size_t)k0 * NMODEL) + col2;

#pragma unroll 8
    for (int k = 0; k < KSLICE; ++k) {
        const float2 w = Wp[(size_t)k * (NMODEL / 2)];
        const float4* __restrict__ xr = (const float4*)&Xs[k][0];
#pragma unroll
        for (int s4 = 0; s4 < 4; ++s4) {
            const float4 xv = xr[s4];
            acc[s4 * 4 + 0].x += xv.x * w.x;  acc[s4 * 4 + 0].y += xv.x * w.y;
            acc[s4 * 4 + 1].x += xv.y * w.x;  acc[s4 * 4 + 1].y += xv.y * w.y;
            acc[s4 * 4 + 2].x += xv.z * w.x;  acc[s4 * 4 + 2].y += xv.z * w.y;
            acc[s4 * 4 + 3].x += xv.w * w.x;  acc[s4 * 4 + 3].y += xv.w * w.y;
        }
    }

    float2* __restrict__ pp =
        (float2*)(part + (size_t)(mat * SPLITK + split) * S_LEN * NMODEL) + col2;
#pragma unroll
    for (int s = 0; s < S_LEN; ++s) pp[(size_t)s * (NMODEL / 2)] = acc[s];
}

// ---------------- Kernel 2: reduce split-K partials ----------------
__global__ __launch_bounds__(256) void qkv_reduce(const float* __restrict__ part,
                                                  float* __restrict__ qkv) {
    const int i4   = blockIdx.x * 256 + threadIdx.x;
    const int flat = i4 * 4;
    const int mat  = flat / (S_LEN * NMODEL);
    const int rem  = flat % (S_LEN * NMODEL);
    float4 sum = {0.f, 0.f, 0.f, 0.f};
#pragma unroll 8
    for (int sp = 0; sp < SPLITK; ++sp) {
        const float4 v = *(const float4*)(part +
            (size_t)(mat * SPLITK + sp) * (S_LEN * NMODEL) + rem);
        sum.x += v.x; sum.y += v.y; sum.z += v.z; sum.w += v.w;
    }
    *(float4*)(qkv + flat) = sum;
}

// ---------------- Kernel 3: flash-decode, MFMA QK^T + VALU PV ----------------
// grid = (NCHT/2 = 64, HHEADS=32), block 128 (2 waves, wave owns 64-row chunk).
// Phase 1: S[16s][64m] via 16x16x32 f16 MFMA (4 row-tiles x 4 k-slices).
//   A (Q):  lane holds Q[s=lane&15][c*32+(lane>>4)*8 + j]   (8 contiguous k)
//   B (K):  lane holds K[row=lane&15][c*32+(lane>>4)*8 + j] (B^T-input pattern)
//   D:      lane holds S[s=(lane>>4)*4+r][row=lane&15]  [guide-verified layout]
// Phase 2/3: round-10 proven softmax + fp32 VALU PV. P-overlap fixed up in fp32.
__global__ __launch_bounds__(128) void attn_partial(const float* __restrict__ qkv,
                                                    const float* __restrict__ cacheK,
                                                    const float* __restrict__ cacheV,
                                                    const int* __restrict__ Pp,
                                                    unsigned short* __restrict__ opart,
                                                    float* __restrict__ mstat,
                                                    float* __restrict__ lstat) {
    const int bx   = blockIdx.x;
    const int h    = blockIdx.y;
    const int tid  = threadIdx.x;
    const int wv   = tid >> 6;
    const int lane = tid & 63;
    const int c    = bx * 2 + wv;
    const int c0   = c * CHUNK_W;
    const int P    = *Pp;
    const int lo   = (P > c0) ? P : c0;
    const int hi_  = (P + S_LEN < c0 + CHUNK_W) ? (P + S_LEN) : (c0 + CHUNK_W);
    const bool overlap = (lo < hi_);         // wave-uniform

    const float* qb = qkv;
    const float* kb = qkv + S_LEN * NMODEL;
    const float* vb = qkv + 2 * S_LEN * NMODEL;

    __shared__ float sct[2][CHUNK_W][SPAD];  // 10.2 KB, scores [m][s]
    __shared__ float ml[2][S_LEN], ll[2][S_LEN];

    const int row16 = lane & 15;             // A: s-row | B: cache-row | D: col
    const int kg    = lane >> 4;             // k-group (phase 1) / s-quad (D)

    // ---- phase 1: QK^T via MFMA ----
    {
        half8 qf[4];
#pragma unroll
        for (int cs = 0; cs < 4; ++cs) {
            const float* qr = qb + row16 * NMODEL + h * DHEAD + cs * 32 + kg * 8;
            qf[cs] = cvt8(*(const float4*)qr, *(const float4*)(qr + 4));
        }
#pragma unroll
        for (int t = 0; t < 4; ++t) {
            const float* krow = cacheK +
                ((size_t)h * MCACHE + c0 + t * 16 + row16) * DHEAD + kg * 8;
            f32x4 acc = {0.f, 0.f, 0.f, 0.f};
#pragma unroll
            for (int cs = 0; cs < 4; ++cs) {
                const float4 ka = *(const float4*)(krow + cs * 32);
                const float4 kc = *(const float4*)(krow + cs * 32 + 4);
                acc = __builtin_amdgcn_mfma_f32_16x16x32_f16(qf[cs], cvt8(ka, kc),
                                                             acc, 0, 0, 0);
            }
            // D: lane -> S[s = kg*4 + r][m = t*16 + row16]
            *(float4*)&sct[wv][t * 16 + row16][kg * 4] = *(float4*)&acc;
        }

        // fixup: recompute overlap rows' scores in exact fp32 with fresh k
        if (overlap) {
            const int sq = kg, dsl = row16, doff = dsl * 8;
            float4 q0[4], q1[4];
#pragma unroll
            for (int j = 0; j < 4; ++j) {
                const int s = sq * 4 + j;
                q0[j] = *(const float4*)(qb + s * NMODEL + h * DHEAD + doff);
                q1[j] = *(const float4*)(qb + s * NMODEL + h * DHEAD + doff + 4);
            }
            for (int gm = lo; gm < hi_; ++gm) {
                const float* kr = kb + (size_t)(gm - P) * NMODEL + h * DHEAD + doff;
                const float4 ka = *(const float4*)(kr);
                const float4 kc = *(const float4*)(kr + 4);
                float pr[4];
#pragma unroll
                for (int j = 0; j < 4; ++j) {
                    pr[j] = ka.x * q0[j].x + ka.y * q0[j].y + ka.z * q0[j].z + ka.w * q0[j].w
                          + kc.x * q1[j].x + kc.y * q1[j].y + kc.z * q1[j].z + kc.w * q1[j].w;
                }
#pragma unroll
                for (int j = 0; j < 4; ++j) {
                    float v = pr[j];
                    v += __shfl_xor(v, 1, 64);
                    v += __shfl_xor(v, 2, 64);
                    v += __shfl_xor(v, 4, 64);
                    v += __shfl_xor(v, 8, 64);
                    pr[j] = v;
                }
                if (dsl == 0) {
                    float4 w; w.x = pr[0]; w.y = pr[1]; w.z = pr[2]; w.w = pr[3];
                    *(float4*)&sct[wv][gm - c0][sq * 4] = w;
                }
            }
        }
    }
    __syncthreads();

    // ---- phase 2: per-s max & sumexp over this wave's 64 rows ----
    {
        for (int s = 0; s < S_LEN; ++s) {
            const float v = sct[wv][lane][s];
            float mx = v;
            for (int off = 32; off > 0; off >>= 1) mx = fmaxf(mx, __shfl_xor(mx, off, 64));
            const float e = __expf(v - mx);
            sct[wv][lane][s] = e;
            float sum = e;
            for (int off = 32; off > 0; off >>= 1) sum += __shfl_xor(sum, off, 64);
            if (lane == 0) { ml[wv][s] = mx; ll[wv][s] = sum; }
        }
    }
    __syncthreads();

    // ---- phase 3: o[s][d] partials; V row read once; p4 via b128 broadcast ----
    {
        const int sq = lane >> 4, dsl = lane & 15, doff = dsl * 8;
        const float* vbase = cacheV + ((size_t)h * MCACHE + c0) * DHEAD + doff;
        float a[4][8];
#pragma unroll
        for (int j = 0; j < 4; ++j)
#pragma unroll
            for (int k = 0; k < 8; ++k) a[j][k] = 0.f;

        for (int m = 0; m < CHUNK_W; ++m) {
            const float4 p4 = *(const float4*)&sct[wv][m][sq * 4];
            const float4 v0 = *(const float4*)(vbase + (size_t)m * DHEAD);
            const float4 v1 = *(const float4*)(vbase + (size_t)m * DHEAD + 4);
            const float pj[4] = {p4.x, p4.y, p4.z, p4.w};
#pragma unroll
            for (int j = 0; j < 4; ++j) {
                a[j][0] += pj[j] * v0.x; a[j][1] += pj[j] * v0.y;
                a[j][2] += pj[j] * v0.z; a[j][3] += pj[j] * v0.w;
                a[j][4] += pj[j] * v1.x; a[j][5] += pj[j] * v1.y;
                a[j][6] += pj[j] * v1.z; a[j][7] += pj[j] * v1.w;
            }
        }

        if (overlap) {                        // stale-V correction: p*(Vnew-Vold)
            for (int gm = lo; gm < hi_; ++gm) {
                const float4 p4 = *(const float4*)&sct[wv][gm - c0][sq * 4];
                const float* vn = vb + (size_t)(gm - P) * NMODEL + h * DHEAD + doff;
                const float* vo = cacheV + ((size_t)h * MCACHE + gm) * DHEAD + doff;
                const float4 n0 = *(const float4*)(vn);
                const float4 n1 = *(const float4*)(vn + 4);
                const float4 o0 = *(const float4*)(vo);
                const float4 o1 = *(const float4*)(vo + 4);
                const float pj[4] = {p4.x, p4.y, p4.z, p4.w};
#pragma unroll
                for (int j = 0; j < 4; ++j) {
                    a[j][0] += pj[j] * (n0.x - o0.x); a[j][1] += pj[j] * (n0.y - o0.y);
                    a[j][2] += pj[j] * (n0.z - o0.z); a[j][3] += pj[j] * (n0.w - o0.w);
                    a[j][4] += pj[j] * (n1.x - o1.x); a[j][5] += pj[j] * (n1.y - o1.y);
                    a[j][6] += pj[j] * (n1.z - o1.z); a[j][7] += pj[j] * (n1.w - o1.w);
                }
            }
        }

        const size_t ob = ((size_t)h * NCHT + c) * S_LEN * DHEAD;
#pragma unroll
        for (int j = 0; j < 4; ++j) {
            const int s = sq * 4 + j;
            uint4 pk;
            unsigned short* us = (unsigned short*)&pk;
#pragma unroll
            for (int k = 0; k < 8; ++k) us[k] = f2h(a[j][k]);
            *(uint4*)&opart[ob + (size_t)s * DHEAD + doff] = pk;
        }
    }

    if (tid < 32) {
        const int w2 = tid >> 4, s = tid & 15;
        const int cc = bx * 2 + w2;
        mstat[((size_t)h * S_LEN + s) * NCHT + cc] = ml[w2][s];
        lstat[((size_t)h * S_LEN + s) * NCHT + cc] = ll[w2][s];
    }
}

// ---------------- Kernel 4: combine chunk partials ----------------
__global__ __launch_bounds__(512) void attn_combine(const unsigned short* __restrict__ opart,
                                                    const float* __restrict__ mstat,
                                                    const float* __restrict__ lstat,
                                                    float* __restrict__ out) {
    const int tid = threadIdx.x;
    const int cg  = tid >> 7;
    const int d   = tid & 127;
    const int s   = blockIdx.x;
    const int h   = blockIdx.y;

    __shared__ float mlds[NCHT], llds[NCHT], wlds[NCHT];
    __shared__ float olds[4][DHEAD];
    __shared__ float Llds[4];

    const size_t sb = ((size_t)h * S_LEN + s) * NCHT;
    if (tid < NCHT) { mlds[tid] = mstat[sb + tid]; llds[tid] = lstat[sb + tid]; }
    __syncthreads();

    float gmax = fmaxf(mlds[tid & 63], mlds[(tid & 63) + 64]);
    for (int off = 32; off > 0; off >>= 1) gmax = fmaxf(gmax, __shfl_xor(gmax, off, 64));

    if (tid < NCHT) wlds[tid] = __expf(mlds[tid] - gmax);
    __syncthreads();

    float o = 0.f, L = 0.f;
    for (int c = cg; c < NCHT; c += 4) {
        const float w = wlds[c];
        o += w * h2f(opart[(((size_t)h * NCHT + c) * S_LEN + s) * DHEAD + d]);
        L += w * llds[c];
    }
    olds[cg][d] = o;
    if (d == 0) Llds[cg] = L;
    __syncthreads();

    if (tid < DHEAD) {
        const float ot = olds[0][tid] + olds[1][tid] + olds[2][tid] + olds[3][tid];
        const float Lt = Llds[0] + Llds[1] + Llds[2] + Llds[3];
        out[((size_t)h * S_LEN + s) * DHEAD + tid] = ot / Lt;
    }
}

extern "C" void kernel_launch(void* const* d_in, const int* in_sizes, int n_in,
                              void* d_out, int out_size, void* d_ws, size_t ws_size,
                              hipStream_t stream) {
    const float* X      = (const float*)d_in[0];
    const float* Wq     = (const float*)d_in[1];
    const float* Wk     = (const float*)d_in[2];
    const float* Wv     = (const float*)d_in[3];
    const float* cacheK = (const float*)d_in[4];
    const float* cacheV = (const float*)d_in[5];
    const int*   P      = (const int*)d_in[6];
    float* out = (float*)d_out;
    float* ws  = (float*)d_ws;

    float*          qkv   = ws;                                  // 196608 floats
    float*          part  = qkv + 3 * S_LEN * NMODEL;
    unsigned short* opart = (unsigned short*)part;               // aliases part
    float*          mstat = part + REGION_ELEMS;
    float*          lstat = mstat + STAT_ELEMS;

    qkv_gemm<<<dim3(8, SPLITK, 3), 256, 0, stream>>>(X, Wq, Wk, Wv, part);
    qkv_reduce<<<(3 * S_LEN * NMODEL / 4) / 256, 256, 0, stream>>>(part, qkv);
    attn_partial<<<dim3(NCHT / 2, HHEADS), 128, 0, stream>>>(qkv, cacheK, cacheV, P,
                                                             opart, mstat, lstat);
    attn_combine<<<dim3(S_LEN, HHEADS), 512, 0, stream>>>(opart, mstat, lstat, out);
}